// Round 1
// 382.087 us; speedup vs baseline: 1.2101x; 1.2101x over previous
//
#include <hip/hip_runtime.h>
#include <math.h>

// Problem constants (from reference)
#define N_NODES 100000
#define N_EDGES 1600000
#define E2      (N_NODES + N_EDGES)   // edges incl. self-loops = 1,700,000
#define IN_C    128
#define HID     64
#define HEADS   4
#define HH      256                    // HEADS*HID
#define OUT_C   2
#define NEG_SLOPE 0.2f

#define SB   1024                      // elements per scan block
#define NSB  ((N_NODES + SB - 1) / SB) // 98
#define NCHUNK 6250                    // fill chunks (6250*256 == N_EDGES)
#define NRANGE 8                       // dst ranges (bands of 12500 nodes)
#define RDIV   12500
#define RT     10                      // row-tiles (16 rows) per gemm3m block
#define NT1    6250                    // gemm1 row-tiles (16 rows each)
#define NGB    1563                    // gemm1 blocks (4 tiles each)
#define NHG    (NCHUNK + NGB)          // fused hist+gemm1 grid = 7813

typedef __attribute__((ext_vector_type(8))) short bf16x8;
typedef __attribute__((ext_vector_type(4))) float f32x4;

__device__ __forceinline__ float bf2f(unsigned short u) {
    return __uint_as_float(((unsigned)u) << 16);
}
__device__ __forceinline__ unsigned short f2bf(float f) {
    unsigned u = __float_as_uint(f);
    u += 0x7fffu + ((u >> 16) & 1u);   // RNE
    return (unsigned short)(u >> 16);
}

// ---------------- CSR build ----------------
// cnt[] counts REAL edges only; degree = cnt+1 (self-loop at slot 0, placed
// by k_scan3). hist emits rank[i] so fill needs NO atomics. Fill is
// range-banded: blocks writing one dst band are contiguous in dispatch order
// so col writes cluster and merge in cache.

// prep (runs first): b<64: W2t transpose; b in [64,66): wsdt; b in [66,98):
// W1t transpose; b in [98,196): zero cnt.
__global__ __launch_bounds__(256) void k_prep(const float* __restrict__ W2,
        const float* __restrict__ W1,
        const float* __restrict__ att_src, const float* __restrict__ att_dst,
        unsigned short* __restrict__ W2t, unsigned short* __restrict__ wsdt,
        unsigned short* __restrict__ W1t, int* __restrict__ cnt) {
    int b = blockIdx.x, t = threadIdx.x;
    if (b < 64) {                       // W2t[n*64+k] = bf16(W2[k][n])
        int g = b * 256 + t;            // g = k*256 + n
        int k = g >> 8, n = g & 255;
        W2t[n * 64 + k] = f2bf(W2[g]);
        return;
    }
    if (b < 66) {                       // wsdt[o*64+k], cols 8..15 zeroed
        int g = (b - 64) * 256 + t;     // 0..511
        wsdt[512 + g] = 0;
        int k = g >> 3, o = g & 7;
        int h = o & 3;
        const float* att = (o < 4) ? att_src : att_dst;
        float acc = 0.f;
        const float* wrow = W2 + (size_t)k * HH + h * 64;
        const float* arow = att + h * 64;
        for (int c = 0; c < 64; ++c) acc = fmaf(wrow[c], arow[c], acc);
        wsdt[o * 64 + k] = f2bf(acc);
        return;
    }
    if (b < 98) {                       // W1t[n*128+k] = bf16(W1[k][n])
        int g = (b - 66) * 256 + t;     // 0..8191, g = k*64 + n
        int k = g >> 6, n = g & 63;
        W1t[n * 128 + k] = f2bf(W1[g]);
        return;
    }
    int i = ((b - 98) * 256 + t) * 4;   // zero cnt
    if (i + 3 < N_NODES) *(int4*)(cnt + i) = make_int4(0, 0, 0, 0);
    else for (int k = 0; k < 4; ++k) if (i + k < N_NODES) cnt[i + k] = 0;
}

// FUSED hist + gemm1: hist is atomic-latency-bound (0.4% VALU, 10% HBM) so
// the independent GEMM1 (x@W1 -> bf16, NO dinv: moved to k_agg1 per-edge)
// hides inside it. 1-in-5 block interleave keeps gemm blocks spread across
// the whole hist window.
__global__ __launch_bounds__(256) void k_hg(const int* __restrict__ ei,
        int* __restrict__ cnt, int* __restrict__ rank,
        const float* __restrict__ x, const unsigned short* __restrict__ W1t,
        unsigned short* __restrict__ xw1b) {
    int b = blockIdx.x;
    if (b % 5 == 2) {                   // GEMM1 block
        int t = threadIdx.x;
        int lane = t & 63, wv = t >> 6;
        int m = lane & 15, quad = lane >> 4;
        bf16x8 B[4][4];
#pragma unroll
        for (int ct = 0; ct < 4; ++ct)
#pragma unroll
            for (int ks = 0; ks < 4; ++ks)
                B[ct][ks] = *(const bf16x8*)(W1t + (size_t)(ct * 16 + m) * IN_C
                                             + ks * 32 + quad * 8);
        int tile = (b / 5) * 4 + wv;
        if (tile >= NT1) return;
        int rbase = tile * 16;
        const float* xp = x + (size_t)(rbase + m) * IN_C + quad * 8;
        f32x4 c0 = {0.f, 0.f, 0.f, 0.f}, c1 = c0, c2 = c0, c3 = c0;
#pragma unroll
        for (int ks = 0; ks < 4; ++ks) {
            float4 f0 = *(const float4*)(xp + ks * 32);
            float4 f1 = *(const float4*)(xp + ks * 32 + 4);
            bf16x8 a;
            a[0] = (short)f2bf(f0.x); a[1] = (short)f2bf(f0.y);
            a[2] = (short)f2bf(f0.z); a[3] = (short)f2bf(f0.w);
            a[4] = (short)f2bf(f1.x); a[5] = (short)f2bf(f1.y);
            a[6] = (short)f2bf(f1.z); a[7] = (short)f2bf(f1.w);
            c0 = __builtin_amdgcn_mfma_f32_16x16x32_bf16(a, B[0][ks], c0, 0, 0, 0);
            c1 = __builtin_amdgcn_mfma_f32_16x16x32_bf16(a, B[1][ks], c1, 0, 0, 0);
            c2 = __builtin_amdgcn_mfma_f32_16x16x32_bf16(a, B[2][ks], c2, 0, 0, 0);
            c3 = __builtin_amdgcn_mfma_f32_16x16x32_bf16(a, B[3][ks], c3, 0, 0, 0);
        }
        int row0 = rbase + quad * 4;
#pragma unroll
        for (int ct = 0; ct < 4; ++ct) {
            f32x4 c = (ct == 0) ? c0 : (ct == 1) ? c1 : (ct == 2) ? c2 : c3;
            unsigned short* p = xw1b + (size_t)row0 * HID + ct * 16 + m;
#pragma unroll
            for (int r = 0; r < 4; ++r) p[(size_t)r * HID] = f2bf(c[r]);
        }
        return;
    }
    // hist block: hidx = b minus #gemm blocks below b
    int hb = b - (b + 2) / 5;
    int i = hb * 256 + threadIdx.x;     // hb in [0,6250): i < N_EDGES exactly
    rank[i] = atomicAdd(&cnt[ei[N_EDGES + i]], 1);
}

// scan1: per-block sums of (cnt+1) -> bsum[NSB]
__global__ __launch_bounds__(256) void k_scan1(const int* __restrict__ cnt,
                                               int* __restrict__ bsum) {
    int b = blockIdx.x, t = threadIdx.x;
    int i = b * SB + t * 4;
    int s = 0;
    if (i + 3 < N_NODES) {
        int4 v = *(const int4*)(cnt + i);
        s = (v.x + v.y) + (v.z + v.w) + 4;       // +1 self-loop per node
    } else {
        for (int k = 0; k < 4; ++k) if (i + k < N_NODES) s += cnt[i + k] + 1;
    }
#pragma unroll
    for (int off = 1; off < 64; off <<= 1) s += __shfl_xor(s, off);
    __shared__ int wsum[4];
    int lane = t & 63, wv = t >> 6;
    if (lane == 0) wsum[wv] = s;
    __syncthreads();
    if (t == 0) bsum[b] = (wsum[0] + wsum[1]) + (wsum[2] + wsum[3]);
}

// scan3: block b computes prefix over bsum[0..b) itself, scans its chunk
// (deg = cnt+1), writes rowptr + dinv, pre-places self-loops at slot 0.
__global__ __launch_bounds__(256) void k_scan3(const int* __restrict__ cnt,
        const int* __restrict__ bsum, int* __restrict__ rowptr,
        float* __restrict__ dinv, int* __restrict__ col) {
    int b = blockIdx.x, t = threadIdx.x;
    int lane = t & 63, wv = t >> 6;
    __shared__ int wred[4];
    {
        int v = (t < b) ? bsum[t] : 0;   // b <= 98 <= 256
#pragma unroll
        for (int off = 1; off < 64; off <<= 1) v += __shfl_xor(v, off);
        if (lane == 0) wred[wv] = v;
    }
    __syncthreads();
    int pre = (wred[0] + wred[1]) + (wred[2] + wred[3]);
    __syncthreads();

    int i = b * SB + t * 4;
    int c0 = 0, c1 = 0, c2 = 0, c3 = 0;
    if (i + 3 < N_NODES) {
        int4 v = *(const int4*)(cnt + i);
        c0 = v.x; c1 = v.y; c2 = v.z; c3 = v.w;
    } else if (i < N_NODES) {
        c0 = cnt[i];
        if (i + 1 < N_NODES) c1 = cnt[i + 1];
        if (i + 2 < N_NODES) c2 = cnt[i + 2];
    }
    int n0 = (i < N_NODES), n1 = (i + 1 < N_NODES),
        n2 = (i + 2 < N_NODES), n3 = (i + 3 < N_NODES);
    int d0 = c0 + n0, d1 = c1 + n1, d2 = c2 + n2, d3 = c3 + n3;  // degrees
    int s = (d0 + d1) + (d2 + d3);
    int inc = s;
#pragma unroll
    for (int off = 1; off < 64; off <<= 1) {
        int u = __shfl_up(inc, off);
        if (lane >= off) inc += u;
    }
    __shared__ int wtot[4];
    if (lane == 63) wtot[wv] = inc;
    __syncthreads();
    int base = pre + (inc - s);
    for (int w = 0; w < wv; ++w) base += wtot[w];
    if (n0) { rowptr[i]     = base;                dinv[i]     = rsqrtf((float)d0); col[base] = i; }
    if (n1) { rowptr[i + 1] = base + d0;           dinv[i + 1] = rsqrtf((float)d1); col[base + d0] = i + 1; }
    if (n2) { rowptr[i + 2] = base + d0 + d1;      dinv[i + 2] = rsqrtf((float)d2); col[base + d0 + d1] = i + 2; }
    if (n3) { rowptr[i + 3] = base + d0 + d1 + d2; dinv[i + 3] = rsqrtf((float)d3); col[base + d0 + d1 + d2] = i + 3; }
    if (b == 0 && t == 0) rowptr[N_NODES] = E2;
}

// fill: atomic-free banded scatter.
__global__ void k_fill(const int* __restrict__ ei, const int* __restrict__ rowptr,
                       const int* __restrict__ rank, int* __restrict__ col) {
    int r = blockIdx.x / NCHUNK;
    int c = blockIdx.x - r * NCHUNK;
    int i = c * 256 + threadIdx.x;          // NCHUNK*256 == N_EDGES exactly
    int d = ei[N_EDGES + i];
    if (d / RDIV != r) return;
    col[rowptr[d] + 1 + rank[i]] = ei[i];   // slot 0 = self-loop
}

// ---------------- GCN1 aggregate: h1b = bf16(relu(dinv*sum + b1)) -----------
// dinv[src] now applied per-edge here (was pre-folded into xw1b) so that
// GEMM1 is independent of the CSR chain and can fuse with hist.
__global__ __launch_bounds__(256) void k_agg1(const int* __restrict__ rowptr,
        const int* __restrict__ col, const unsigned short* __restrict__ xw1b,
        const float* __restrict__ dinv, const float* __restrict__ b1,
        unsigned short* __restrict__ h1b) {
    int t = threadIdx.x;
    int lane = t & 63;
    int d = blockIdx.x * 4 + (t >> 6);
    if (d >= N_NODES) return;
    int start = rowptr[d], end = rowptr[d + 1];
    int sub = lane >> 4;       // which of 4 edges in a group
    int cpos = lane & 15;      // channel quad (4 bf16)
    float4 acc = make_float4(0.f, 0.f, 0.f, 0.f);
    for (int base = start; base < end; base += 64) {
        int cnt = min(64, end - base);
        int sl = (base + lane < end) ? col[base + lane] : 0;
#pragma unroll 2
        for (int j = 0; j < cnt; j += 4) {
            int idx = j + sub;
            int sj = __shfl(sl, idx);
            if (idx < cnt) {
                float di = dinv[sj];
                ushort4 v = ((const ushort4*)(xw1b + (size_t)sj * HID))[cpos];
                acc.x = fmaf(di, bf2f(v.x), acc.x);
                acc.y = fmaf(di, bf2f(v.y), acc.y);
                acc.z = fmaf(di, bf2f(v.z), acc.z);
                acc.w = fmaf(di, bf2f(v.w), acc.w);
            }
        }
    }
    acc.x += __shfl_xor(acc.x, 16); acc.y += __shfl_xor(acc.y, 16);
    acc.z += __shfl_xor(acc.z, 16); acc.w += __shfl_xor(acc.w, 16);
    acc.x += __shfl_xor(acc.x, 32); acc.y += __shfl_xor(acc.y, 32);
    acc.z += __shfl_xor(acc.z, 32); acc.w += __shfl_xor(acc.w, 32);
    if (lane < 16) {
        float di = dinv[d];
        float4 b = ((const float4*)b1)[lane];
        float ox = fmaf(acc.x, di, b.x); ox = ox > 0.f ? ox : 0.f;
        float oy = fmaf(acc.y, di, b.y); oy = oy > 0.f ? oy : 0.f;
        float oz = fmaf(acc.z, di, b.z); oz = oz > 0.f ? oz : 0.f;
        float ow = fmaf(acc.w, di, b.w); ow = ow > 0.f ? ow : 0.f;
        ushort4 o = make_ushort4(f2bf(ox), f2bf(oy), f2bf(oz), f2bf(ow));
        ((ushort4*)(h1b + (size_t)d * HID))[lane] = o;
    }
}

// ---------------- attention logits: a_s, a_d via MFMA (tiny) ----------------
// xw2b is no longer materialized: a_s/a_d only need h1 @ (W2·att) = wsdt.
__global__ __launch_bounds__(256) void k_attn(const unsigned short* __restrict__ h1b,
        const unsigned short* __restrict__ wsdt,
        float* __restrict__ a_s, float* __restrict__ a_d) {
    int t = threadIdx.x;
    int lane = t & 63, wv = t >> 6;
    int m = lane & 15, quad = lane >> 4;
    bf16x8 Bw0 = *(const bf16x8*)(wsdt + (size_t)m * 64 + quad * 8);
    bf16x8 Bw1 = *(const bf16x8*)(wsdt + (size_t)m * 64 + 32 + quad * 8);
    int tile = blockIdx.x * 4 + wv;
    if (tile >= NT1) return;
    int rbase = tile * 16;
    const unsigned short* ap = h1b + (size_t)(rbase + m) * 64 + quad * 8;
    bf16x8 a0 = *(const bf16x8*)(ap);
    bf16x8 a1 = *(const bf16x8*)(ap + 32);
    f32x4 aw = {0.f, 0.f, 0.f, 0.f};
    aw = __builtin_amdgcn_mfma_f32_16x16x32_bf16(a0, Bw0, aw, 0, 0, 0);
    aw = __builtin_amdgcn_mfma_f32_16x16x32_bf16(a1, Bw1, aw, 0, 0, 0);
    int row = rbase + quad * 4;
    if (m < 4) {
#pragma unroll
        for (int r = 0; r < 4; ++r) a_s[(row + r) * 4 + m] = aw[r];
    } else if (m < 8) {
#pragma unroll
        for (int r = 0; r < 4; ++r) a_d[(row + r) * 4 + (m - 4)] = aw[r];
    }
}

// ---------------- GAT aggregate on h1 (ALGEBRA: agg commutes with W2) -------
// sum_e alpha_e*(h1[s]·W2) == (sum_e alpha_e*h1[s])·W2, so gather 128 B/edge
// (h1 row) instead of 512 B/edge (xw2 row). Emits ub[d][h*64+c] = bf16 of the
// alpha-normalized per-head aggregate; W2-apply moves to k_gemm3m.
// TWO half-range dispatches kept (profiling-window visibility).
__global__ __launch_bounds__(256) void k_agg2u(const int* __restrict__ rowptr,
        const int* __restrict__ col, const unsigned short* __restrict__ h1b,
        const float* __restrict__ a_s, const float* __restrict__ a_d,
        unsigned short* __restrict__ ub, int dbase) {
    __shared__ int   ss[4][64];      // 1 KB
    __shared__ float sp[4][64][4];   // 4 KB
    int t = threadIdx.x;
    int lane = t & 63, wv = t >> 6;
    int d = dbase + blockIdx.x * 4 + wv;
    if (d >= N_NODES) return;
    const float4* as4 = (const float4*)a_s;
    float4 adv = ((const float4*)a_d)[d];
    int start = rowptr[d], end = rowptr[d + 1];

    float den0 = 0.f, den1 = 0.f, den2 = 0.f, den3 = 0.f;
    float acc0 = 0.f, acc1 = 0.f, acc2 = 0.f, acc3 = 0.f;
    for (int base = start; base < end; base += 64) {
        int cnt = min(64, end - base);
        float p0 = 0.f, p1 = 0.f, p2 = 0.f, p3 = 0.f;
        int s = 0;
        if (lane < cnt) {
            s = col[base + lane];
            float4 av = as4[s];
            float v;
            v = av.x + adv.x; v = v > 0.f ? v : NEG_SLOPE * v; p0 = __expf(v);
            v = av.y + adv.y; v = v > 0.f ? v : NEG_SLOPE * v; p1 = __expf(v);
            v = av.z + adv.z; v = v > 0.f ? v : NEG_SLOPE * v; p2 = __expf(v);
            v = av.w + adv.w; v = v > 0.f ? v : NEG_SLOPE * v; p3 = __expf(v);
            den0 += p0; den1 += p1; den2 += p2; den3 += p3;
        }
        ss[wv][lane] = s;                                  // wave-private LDS
        ((float4*)sp[wv])[lane] = make_float4(p0, p1, p2, p3);
#pragma unroll 4
        for (int j = 0; j < cnt; ++j) {
            int sj = ss[wv][j];                            // broadcast read
            float4 pj = ((const float4*)sp[wv])[j];        // broadcast read
            float v = bf2f(h1b[(unsigned)sj * 64u + (unsigned)lane]); // 2B/lane
            acc0 = fmaf(pj.x, v, acc0);
            acc1 = fmaf(pj.y, v, acc1);
            acc2 = fmaf(pj.z, v, acc2);
            acc3 = fmaf(pj.w, v, acc3);
        }
    }
#pragma unroll
    for (int mk = 1; mk < 64; mk <<= 1) {
        den0 += __shfl_xor(den0, mk);
        den1 += __shfl_xor(den1, mk);
        den2 += __shfl_xor(den2, mk);
        den3 += __shfl_xor(den3, mk);
    }
    float u0 = acc0 / (den0 + 1e-16f);
    float u1 = acc1 / (den1 + 1e-16f);
    float u2 = acc2 / (den2 + 1e-16f);
    float u3 = acc3 / (den3 + 1e-16f);
    unsigned short* up = ub + (size_t)d * HH;
    up[lane]       = f2bf(u0);
    up[64 + lane]  = f2bf(u1);
    up[128 + lane] = f2bf(u2);
    up[192 + lane] = f2bf(u3);
}

// ---------------- W2-apply + b2 + ELU + W3 + dinv, via MFMA -----------------
// Same fragment structure as the old k_gemm2m (head h == wave wv; W2 is
// block-diagonal over heads so B-fragments come straight from W2t).
__global__ __launch_bounds__(256) void k_gemm3m(const unsigned short* __restrict__ ub,
        const unsigned short* __restrict__ W2t, const float* __restrict__ b2,
        const float* __restrict__ W3, const float* __restrict__ dinv,
        float2* __restrict__ xw3) {
    int t = threadIdx.x;
    int lane = t & 63, wv = t >> 6;
    int m = lane & 15, quad = lane >> 4;
    int nb = wv * 64 + m;            // lane's base output column (head = wv)
    bf16x8 B[4][2];
#pragma unroll
    for (int ct = 0; ct < 4; ++ct)
#pragma unroll
        for (int ks = 0; ks < 2; ++ks)
            B[ct][ks] = *(const bf16x8*)(W2t + (size_t)(nb + ct * 16) * 64
                                         + ks * 32 + quad * 8);
    float bv[4]; float2 w3v[4];
#pragma unroll
    for (int ct = 0; ct < 4; ++ct) {
        int n = nb + ct * 16;
        bv[ct] = b2[n];
        w3v[ct] = ((const float2*)W3)[n];
    }
    __shared__ float red[4][16][2];  // [wave][row][xy]
    int r0 = blockIdx.x * (RT * 16);
    for (int tile = 0; tile < RT; ++tile) {
        int rbase = r0 + tile * 16;
        const unsigned short* ap = ub + (size_t)(rbase + m) * HH + wv * 64 + quad * 8;
        bf16x8 a0 = *(const bf16x8*)(ap);
        bf16x8 a1 = *(const bf16x8*)(ap + 32);
        f32x4 c0 = {0.f, 0.f, 0.f, 0.f}, c1 = c0, c2 = c0, c3 = c0;
        c0 = __builtin_amdgcn_mfma_f32_16x16x32_bf16(a0, B[0][0], c0, 0, 0, 0);
        c1 = __builtin_amdgcn_mfma_f32_16x16x32_bf16(a0, B[1][0], c1, 0, 0, 0);
        c2 = __builtin_amdgcn_mfma_f32_16x16x32_bf16(a0, B[2][0], c2, 0, 0, 0);
        c3 = __builtin_amdgcn_mfma_f32_16x16x32_bf16(a0, B[3][0], c3, 0, 0, 0);
        c0 = __builtin_amdgcn_mfma_f32_16x16x32_bf16(a1, B[0][1], c0, 0, 0, 0);
        c1 = __builtin_amdgcn_mfma_f32_16x16x32_bf16(a1, B[1][1], c1, 0, 0, 0);
        c2 = __builtin_amdgcn_mfma_f32_16x16x32_bf16(a1, B[2][1], c2, 0, 0, 0);
        c3 = __builtin_amdgcn_mfma_f32_16x16x32_bf16(a1, B[3][1], c3, 0, 0, 0);
        // C/D: col = nb + ct*16, row = rbase + quad*4 + r
        float px[4] = {0.f, 0.f, 0.f, 0.f}, py[4] = {0.f, 0.f, 0.f, 0.f};
#pragma unroll
        for (int ct = 0; ct < 4; ++ct) {
            f32x4 c = (ct == 0) ? c0 : (ct == 1) ? c1 : (ct == 2) ? c2 : c3;
#pragma unroll
            for (int r = 0; r < 4; ++r) {
                float o = c[r] + bv[ct];
                o = o > 0.f ? o : expm1f(o);               // ELU
                px[r] = fmaf(o, w3v[ct].x, px[r]);
                py[r] = fmaf(o, w3v[ct].y, py[r]);
            }
        }
#pragma unroll
        for (int mk = 1; mk < 16; mk <<= 1) {
#pragma unroll
            for (int r = 0; r < 4; ++r) {
                px[r] += __shfl_xor(px[r], mk);
                py[r] += __shfl_xor(py[r], mk);
            }
        }
        if (m == 0) {
#pragma unroll
            for (int r = 0; r < 4; ++r) {
                red[wv][quad * 4 + r][0] = px[r];
                red[wv][quad * 4 + r][1] = py[r];
            }
        }
        __syncthreads();
        if (t < 32) {
            int row = t >> 1, xy = t & 1;
            float s = red[0][row][xy] + red[1][row][xy]
                    + red[2][row][xy] + red[3][row][xy];
            ((float*)(xw3 + (rbase + row)))[xy] = s * dinv[rbase + row];
        }
        __syncthreads();
    }
}

// ---------------- GCN2 aggregate: out = dinv[d]*sum_s xw3[s] + b3 -----------
// 4 lanes per dst: serial dependent-load chain 17 -> ~4.
__global__ __launch_bounds__(256) void k_agg3(const int* __restrict__ rowptr,
        const int* __restrict__ col, const float2* __restrict__ xw3,
        const float* __restrict__ dinv, const float* __restrict__ b3,
        float* __restrict__ out) {
    int t = threadIdx.x;
    int lane = t & 63;
    int g = lane >> 2, s = lane & 3;
    int d = blockIdx.x * 64 + (t >> 6) * 16 + g;
    if (d >= N_NODES) return;
    int e0 = rowptr[d], e1 = rowptr[d + 1];
    float a0 = 0.f, a1 = 0.f;
    for (int e = e0 + s; e < e1; e += 4) {
        float2 v = xw3[col[e]];
        a0 += v.x; a1 += v.y;
    }
    a0 += __shfl_xor(a0, 1); a1 += __shfl_xor(a1, 1);
    a0 += __shfl_xor(a0, 2); a1 += __shfl_xor(a1, 2);
    if (s == 0) {
        float di = dinv[d];
        out[d * 2 + 0] = fmaf(a0, di, b3[0]);
        out[d * 2 + 1] = fmaf(a1, di, b3[1]);
    }
}

// ---------------- launch ----------------

extern "C" void kernel_launch(void* const* d_in, const int* in_sizes, int n_in,
                              void* d_out, int out_size, void* d_ws, size_t ws_size,
                              hipStream_t stream) {
    const float* x       = (const float*)d_in[0];
    const int*   ei      = (const int*)d_in[1];
    const float* W1      = (const float*)d_in[2];
    const float* b1      = (const float*)d_in[3];
    const float* W2      = (const float*)d_in[4];
    const float* att_src = (const float*)d_in[5];
    const float* att_dst = (const float*)d_in[6];
    const float* b2      = (const float*)d_in[7];
    const float* W3      = (const float*)d_in[8];
    const float* b3      = (const float*)d_in[9];
    float* out = (float*)d_out;
    (void)in_sizes; (void)n_in; (void)out_size; (void)ws_size;

    char* ws = (char*)d_ws;
    size_t off = 0;
    auto alloc = [&](size_t bytes) -> void* {
        void* p = ws + off;
        off = (off + bytes + 255) & ~(size_t)255;
        return p;
    };
    int*    rowptr = (int*)alloc((N_NODES + 1) * sizeof(int));
    int*    cnt    = (int*)alloc(N_NODES * sizeof(int));
    int*    bsum   = (int*)alloc(NSB * sizeof(int));
    int*    rank   = (int*)alloc((size_t)N_EDGES * sizeof(int));
    int*    col    = (int*)alloc((size_t)E2 * sizeof(int));
    float*  dinv   = (float*)alloc(N_NODES * sizeof(float));
    unsigned short* W2t  = (unsigned short*)alloc(64 * 256 * sizeof(unsigned short));
    unsigned short* wsdt = (unsigned short*)alloc(16 * 64 * sizeof(unsigned short));
    unsigned short* W1t  = (unsigned short*)alloc(64 * 128 * sizeof(unsigned short));
    unsigned short* xw1b = (unsigned short*)alloc((size_t)N_NODES * HID * sizeof(unsigned short));
    unsigned short* h1b  = (unsigned short*)alloc((size_t)N_NODES * HID * sizeof(unsigned short));
    float*  a_s    = (float*)alloc((size_t)N_NODES * HEADS * sizeof(float));
    float*  a_d    = (float*)alloc((size_t)N_NODES * HEADS * sizeof(float));
    unsigned short* ub   = (unsigned short*)alloc((size_t)N_NODES * HH * sizeof(unsigned short));
    float2* xw3    = (float2*)alloc((size_t)N_NODES * sizeof(float2));

    k_prep<<<196, 256, 0, stream>>>(W2, W1, att_src, att_dst, W2t, wsdt, W1t, cnt);
    k_hg<<<NHG, 256, 0, stream>>>(ei, cnt, rank, x, W1t, xw1b);
    k_scan1<<<NSB, 256, 0, stream>>>(cnt, bsum);
    k_scan3<<<NSB, 256, 0, stream>>>(cnt, bsum, rowptr, dinv, col);
    k_fill<<<NCHUNK * NRANGE, 256, 0, stream>>>(ei, rowptr, rank, col);

    k_agg1<<<(N_NODES + 3) / 4, 256, 0, stream>>>(rowptr, col, xw1b, dinv, b1, h1b);
    k_attn<<<(NT1 + 3) / 4, 256, 0, stream>>>(h1b, wsdt, a_s, a_d);
    const int HALF = 50000;                       // nodes per half
    k_agg2u<<<HALF / 4, 256, 0, stream>>>(rowptr, col, h1b, a_s, a_d, ub, 0);
    k_agg2u<<<(N_NODES - HALF + 3) / 4, 256, 0, stream>>>(rowptr, col, h1b, a_s, a_d, ub, HALF);
    k_gemm3m<<<(N_NODES / 16) / RT, 256, 0, stream>>>(ub, W2t, b2, W3, dinv, xw3);
    k_agg3<<<(N_NODES + 63) / 64, 256, 0, stream>>>(rowptr, col, xw3, dinv, b3, out);
}